// Round 6
// baseline (241.618 us; speedup 1.0000x reference)
//
#include <hip/hip_runtime.h>

#define BB 64
#define CC 128
#define TT 4096
#define NN 6            // KNOT + 2
#define HH 819.0f       // (T-1)/(KNOT+1) = 4095/5, exact in fp32
#define NTHR 256
#define EPT 16          // curve elements per thread (NTHR*EPT == TT)
#define NWAVE (NTHR / 64)
#define NROW (BB * CC)
#define NSPAN 5
#define TABBYTES ((size_t)NROW * NSPAN * 16)
#define PADSZ (TT + TT / 32)

typedef float f4 __attribute__((ext_vector_type(4)));

__device__ __forceinline__ void nt_store4(float* p, f4 v) {
    __builtin_nontemporal_store(v, (f4*)p);
}

// LDS pad: +1 float per 32 breaks power-of-2 stride conflicts.
__device__ __forceinline__ int padi(int j) { return j + (j >> 5); }

// ---- 6x6 not-a-knot solve; A compile-time constant -> multipliers fold ----
__device__ __forceinline__ void spline_solve(const float* __restrict__ yy,
                                             int b, int c, float* y, float* Mv)
{
    #pragma unroll
    for (int k = 0; k < NN; ++k)
        y[k] = yy[((size_t)b * NN + k) * CC + c];
    float Aug[NN][NN + 1];
    #pragma unroll
    for (int i = 0; i < NN; ++i)
        #pragma unroll
        for (int j = 0; j < NN + 1; ++j)
            Aug[i][j] = 0.0f;
    Aug[0][0] = 1.0f;  Aug[0][1] = -2.0f;  Aug[0][2] = 1.0f;
    Aug[5][3] = 1.0f;  Aug[5][4] = -2.0f;  Aug[5][5] = 1.0f;
    #pragma unroll
    for (int i = 1; i < NN - 1; ++i) {
        Aug[i][i - 1] = HH / 6.0f;
        Aug[i][i]     = 2.0f * HH / 3.0f;
        Aug[i][i + 1] = HH / 6.0f;
        Aug[i][NN]    = (y[i + 1] - 2.0f * y[i] + y[i - 1]) / HH;
    }
    #pragma unroll
    for (int k = 0; k < NN; ++k) {
        float inv = 1.0f / Aug[k][k];
        #pragma unroll
        for (int i = k + 1; i < NN; ++i) {
            float m = Aug[i][k] * inv;
            #pragma unroll
            for (int j = k; j < NN + 1; ++j)
                Aug[i][j] -= m * Aug[k][j];
        }
    }
    #pragma unroll
    for (int i = NN - 1; i >= 0; --i) {
        float s = Aug[i][NN];
        #pragma unroll
        for (int j = i + 1; j < NN; ++j)
            s -= Aug[i][j] * Mv[j];
        Mv[i] = s / Aug[i][i];
    }
}

__device__ __forceinline__ void horner_coefs(const float* y, const float* Mv,
                                             f4* out5)
{
    const float invh  = 1.0f / HH;
    const float inv6h = 1.0f / (6.0f * HH);
    #pragma unroll
    for (int s = 0; s < NSPAN; ++s) {
        f4 cf;
        cf.x = y[s];
        cf.y = (y[s + 1] - y[s]) * invh - Mv[s] * (HH / 3.0f) - Mv[s + 1] * (HH / 6.0f);
        cf.z = Mv[s] * 0.5f;
        cf.w = (Mv[s + 1] - Mv[s]) * inv6h;
        out5[s] = cf;
    }
}

// ---- setup: per-(row, span) Horner coeffs (a,b,c,d) into workspace ----
__global__ __launch_bounds__(256) void spline_coef_kernel(
    const float* __restrict__ yy, f4* __restrict__ tab)
{
    const int row = blockIdx.x * 256 + threadIdx.x;   // 8192 rows, coalesced in c
    const int b = row / CC;
    const int c = row % CC;
    float y[NN], Mv[NN];
    spline_solve(yy, b, c, y, Mv);
    f4 cf[NSPAN];
    horner_coefs(y, Mv, cf);
    #pragma unroll
    for (int s = 0; s < NSPAN; ++s)
        tab[row * NSPAN + s] = cf[s];
}

// ============================ main kernel ==================================
// 1 row/block, 256 threads x 16 elems. TABLE=1: coeffs from workspace.
// __launch_bounds__(256,6): >=6 waves/SIMD -> >=6 blocks/CU resident.
template <int TABLE>
__global__ __launch_bounds__(NTHR, 6) void timewarp_kernel(
    const float* __restrict__ x,
    const float* __restrict__ yy,
    const float* __restrict__ mask_rand,
    const f4* __restrict__ tab,
    float* __restrict__ out)
{
    const int row = blockIdx.x;          // b*C + c
    const int b   = row / CC;
    const int tid = threadIdx.x;

    const float* xrow = x + (size_t)row * TT;
    float* orow       = out + (size_t)row * TT;

    // mask_rand >= 0.5 -> bit-exact copy (uniform per block)
    if (!(mask_rand[b] < 0.5f)) {
        const f4* xi = (const f4*)xrow;
        #pragma unroll
        for (int k = 0; k < 4; ++k)
            nt_store4(orow + 4 * (tid + NTHR * k), xi[tid + NTHR * k]);
        return;
    }

    __shared__ float sh_res[PADSZ];      // padded scatter target
    __shared__ float sh_wsum[NWAVE];     // per-wave scan totals

    // ---- span geometry ----
    const int t0 = tid * EPT;
    int idxA = t0 / 819;  if (idxA > 4) idxA = 4;
    int idxB = idxA + 1;  if (idxB > 4) idxB = 4;
    const float xlA = (float)idxA * HH;
    const float xlB = (float)idxB * HH;
    const float tb  = (float)((idxA + 1) * 819);   // first t belonging to span B

    // ---- all global loads issued up front ----
    float fpv[EPT];
    {
        #pragma unroll
        for (int q = 0; q < 4; ++q) {
            const f4 v = *(const f4*)(xrow + t0 + 4 * q);
            fpv[4 * q + 0] = v.x; fpv[4 * q + 1] = v.y;
            fpv[4 * q + 2] = v.z; fpv[4 * q + 3] = v.w;
        }
    }
    // neighbor's first fp value, bit-identical bits from global (L1-hot)
    const float fpb = xrow[(t0 + EPT < TT) ? (t0 + EPT) : (TT - 1)];

    f4 cfA, cfB;
    if (TABLE) {
        cfA = tab[row * NSPAN + idxA];   // lanes share spans -> few lines/wave
        cfB = tab[row * NSPAN + idxB];
    } else {
        float y[NN], Mv[NN];
        f4 cf[NSPAN];
        spline_solve(yy, b, row % CC, y, Mv);
        horner_coefs(y, Mv, cf);
        cfA = cf[0];  cfB = cf[0];
        #pragma unroll
        for (int s = 1; s < NSPAN; ++s) {      // static indices -> cndmask
            if (idxA >= s) cfA = cf[s];
            if (idxB >= s) cfB = cf[s];
        }
    }

    // ---- curve + thread-local inclusive scan (in-place in xp[]) ----
    float xp[EPT + 1];
    float running = 0.0f;
    #pragma unroll
    for (int k = 0; k < EPT; ++k) {
        float ft = (float)(t0 + k);
        bool inB = ft >= tb;
        f4    cf = inB ? cfB : cfA;
        float xl = inB ? xlB : xlA;
        float s  = ft - xl;
        running += fmaf(s, fmaf(s, fmaf(s, cf.w, cf.z), cf.y), cf.x);
        xp[k] = running;
    }
    // curve at t0+EPT (for the lane-63 boundary reconstruction)
    float cN;
    {
        float ft = (float)(t0 + EPT);
        bool inB = ft >= tb;
        f4    cf = inB ? cfB : cfA;
        float xl = inB ? xlB : xlA;
        float s  = ft - xl;
        cN = fmaf(s, fmaf(s, fmaf(s, cf.w, cf.z), cf.y), cf.x);
    }

    // ---- wave scan (shfl) + cross-wave fixup (barrier 1) ----
    const int lane = tid & 63, wid = tid >> 6;
    float ws = running;
    #pragma unroll
    for (int d = 1; d < 64; d <<= 1) {
        float v = __shfl_up(ws, d, 64);
        if (lane >= d) ws += v;
    }
    if (lane == 63) sh_wsum[wid] = ws;
    __syncthreads();                            // B1
    float wo = 0.0f, total = 0.0f;
    #pragma unroll
    for (int w = 0; w < NWAVE; ++w) {           // ascending: order matters for
        float s = sh_wsum[w];                   // the lane-63 bit-exact proof
        total += s;
        if (w < wid) wo += s;
    }
    const float offs  = wo + (ws - running);    // exclusive prefix
    const float scale = 4095.0f / total;

    #pragma unroll
    for (int k = 0; k < EPT; ++k)
        xp[k] = (xp[k] + offs) * scale;

    // Boundary xp[EPT] without a barrier (validated in prior round):
    //  lanes 0..62: shfl_down of neighbor's xp[0] -> exact bits.
    //  lane 63: ((wo + ws) + cN) * scale. Neighbor (lane 0, wave wid+1):
    //    (lc[0] + of')*scale, lc[0] = 0 + cN = cN, of' = wo' + 0, wo' =
    //    ascending sum w<=wid = wo (+) ws in the same order -> cN + wo'
    //    == (wo+ws)+cN by IEEE commutativity: bit-identical, coverage
    //    stays telescoping/gap-free.
    {
        float n = __shfl_down(xp[0], 1, 64);
        float l = ((wo + ws) + cN) * scale;
        xp[EPT] = (lane == 63) ? l : n;         // tid NTHR-1: unused
    }

    // ---- direct forward scatter of final values ----
    // segment j owns q in [ceil(xp[j]), ceil(xp[j+1])-1]
    #pragma unroll
    for (int k = 0; k < EPT; ++k) {
        const int seg = t0 + k;
        if (seg < TT - 1) {
            float xa = xp[k], xb = xp[k + 1];
            float fa = fpv[k];
            float fb = (k < EPT - 1) ? fpv[k + 1] : fpb;
            float d  = xb - xa;
            float slope = (d > 0.0f) ? (fb - fa) * __builtin_amdgcn_rcpf(d) : 0.0f;
            float a0 = fmaf(-xa, slope, fa);
            int qlo = (int)ceilf(xa);  if (qlo < 0) qlo = 0;
            int qhi = (int)ceilf(xb);  if (qhi > TT) qhi = TT;
            for (int q = qlo; q < qhi; ++q)
                sh_res[padi(q)] = fmaf((float)q, slope, a0);
        }
    }
    if (tid == 0) {                             // head: q < xp[0] -> fp[0]
        int q1 = (int)ceilf(xp[0]);  if (q1 > TT) q1 = TT;
        for (int q = 0; q < q1; ++q) sh_res[padi(q)] = fpv[0];
    }
    if (tid == NTHR - 1) {                      // tail: q >= xp[4095] -> fp[4095]
        int q0 = (int)ceilf(xp[EPT - 1]);  if (q0 < 0) q0 = 0;
        for (int q = q0; q < TT; ++q) sh_res[padi(q)] = fpv[EPT - 1];
    }
    __syncthreads();                            // B2: sh_res complete

    // ---- restage: coalesced nontemporal float4 stores ----
    #pragma unroll
    for (int kk = 0; kk < 4; ++kk) {
        int i4  = tid + NTHR * kk;
        int fb4 = 4 * i4;
        int p   = padi(fb4);
        f4 v;
        v.x = sh_res[p + 0];
        v.y = sh_res[p + 1];
        v.z = sh_res[p + 2];
        v.w = sh_res[p + 3];
        nt_store4(orow + fb4, v);
    }
}

extern "C" void kernel_launch(void* const* d_in, const int* in_sizes, int n_in,
                              void* d_out, int out_size, void* d_ws, size_t ws_size,
                              hipStream_t stream) {
    const float* x    = (const float*)d_in[0];   // (64,128,4096) fp32
    const float* yy   = (const float*)d_in[1];   // (64,6,128)    fp32
    const float* mask = (const float*)d_in[2];   // (64,1,1)      fp32
    float* out = (float*)d_out;                  // (64,128,4096) fp32

    if (d_ws != nullptr && ws_size >= TABBYTES) {
        f4* tab = (f4*)d_ws;
        spline_coef_kernel<<<dim3(NROW / 256), dim3(256), 0, stream>>>(yy, tab);
        timewarp_kernel<1><<<dim3(NROW), dim3(NTHR), 0, stream>>>(x, yy, mask, tab, out);
    } else {
        timewarp_kernel<0><<<dim3(NROW), dim3(NTHR), 0, stream>>>(x, yy, mask, nullptr, out);
    }
}

// Round 7
// 239.061 us; speedup vs baseline: 1.0107x; 1.0107x over previous
//
#include <hip/hip_runtime.h>

#define BB 64
#define CC 128
#define TT 4096
#define NN 6            // KNOT + 2
#define HH 819.0f       // (T-1)/(KNOT+1) = 4095/5, exact in fp32
#define NTHR 256
#define EPT 16          // curve elements per thread (NTHR*EPT == TT)
#define NWAVE (NTHR / 64)
#define NROW (BB * CC)
#define NSPAN 5
#define TABBYTES ((size_t)NROW * NSPAN * 16)
#define NSEED 1024      // one seed per 4 output q's (GS = 4)
#define XFSZ 4224       // p2(4095) = 4222, round up

typedef float f4 __attribute__((ext_vector_type(4)));

__device__ __forceinline__ void nt_store4(float* p, f4 v) {
    __builtin_nontemporal_store(v, (f4*)p);
}

// float2-array pad: +1 slot per 32 spreads stride-4 gather reads to the
// 4-way floor (free-ish per bank model); index in float2 units.
__device__ __forceinline__ int p2(int j) { return j + (j >> 5); }

// ---- 6x6 not-a-knot solve; A compile-time constant -> multipliers fold ----
__device__ __forceinline__ void spline_solve(const float* __restrict__ yy,
                                             int b, int c, float* y, float* Mv)
{
    #pragma unroll
    for (int k = 0; k < NN; ++k)
        y[k] = yy[((size_t)b * NN + k) * CC + c];
    float Aug[NN][NN + 1];
    #pragma unroll
    for (int i = 0; i < NN; ++i)
        #pragma unroll
        for (int j = 0; j < NN + 1; ++j)
            Aug[i][j] = 0.0f;
    Aug[0][0] = 1.0f;  Aug[0][1] = -2.0f;  Aug[0][2] = 1.0f;
    Aug[5][3] = 1.0f;  Aug[5][4] = -2.0f;  Aug[5][5] = 1.0f;
    #pragma unroll
    for (int i = 1; i < NN - 1; ++i) {
        Aug[i][i - 1] = HH / 6.0f;
        Aug[i][i]     = 2.0f * HH / 3.0f;
        Aug[i][i + 1] = HH / 6.0f;
        Aug[i][NN]    = (y[i + 1] - 2.0f * y[i] + y[i - 1]) / HH;
    }
    #pragma unroll
    for (int k = 0; k < NN; ++k) {
        float inv = 1.0f / Aug[k][k];
        #pragma unroll
        for (int i = k + 1; i < NN; ++i) {
            float m = Aug[i][k] * inv;
            #pragma unroll
            for (int j = k; j < NN + 1; ++j)
                Aug[i][j] -= m * Aug[k][j];
        }
    }
    #pragma unroll
    for (int i = NN - 1; i >= 0; --i) {
        float s = Aug[i][NN];
        #pragma unroll
        for (int j = i + 1; j < NN; ++j)
            s -= Aug[i][j] * Mv[j];
        Mv[i] = s / Aug[i][i];
    }
}

__device__ __forceinline__ void horner_coefs(const float* y, const float* Mv,
                                             f4* out5)
{
    const float invh  = 1.0f / HH;
    const float inv6h = 1.0f / (6.0f * HH);
    #pragma unroll
    for (int s = 0; s < NSPAN; ++s) {
        f4 cf;
        cf.x = y[s];
        cf.y = (y[s + 1] - y[s]) * invh - Mv[s] * (HH / 3.0f) - Mv[s + 1] * (HH / 6.0f);
        cf.z = Mv[s] * 0.5f;
        cf.w = (Mv[s + 1] - Mv[s]) * inv6h;
        out5[s] = cf;
    }
}

// ---- setup: per-(row, span) Horner coeffs (a,b,c,d) into workspace ----
__global__ __launch_bounds__(256) void spline_coef_kernel(
    const float* __restrict__ yy, f4* __restrict__ tab)
{
    const int row = blockIdx.x * 256 + threadIdx.x;   // 8192 rows, coalesced in c
    const int b = row / CC;
    const int c = row % CC;
    float y[NN], Mv[NN];
    spline_solve(yy, b, c, y, Mv);
    f4 cf[NSPAN];
    horner_coefs(y, Mv, cf);
    #pragma unroll
    for (int s = 0; s < NSPAN; ++s)
        tab[row * NSPAN + s] = cf[s];
}

// ============================ main kernel ==================================
// 1 row/block, 256 threads x 16 elems. Seeded merge-GATHER (no scatter, no
// restage). TABLE=1: coeffs from workspace.
template <int TABLE>
__global__ __launch_bounds__(NTHR, 4) void timewarp_kernel(
    const float* __restrict__ x,
    const float* __restrict__ yy,
    const float* __restrict__ mask_rand,
    const f4* __restrict__ tab,
    float* __restrict__ out)
{
    const int row = blockIdx.x;          // b*C + c
    const int b   = row / CC;
    const int tid = threadIdx.x;

    const float* xrow = x + (size_t)row * TT;
    float* orow       = out + (size_t)row * TT;

    // mask_rand >= 0.5 -> bit-exact copy (uniform per block)
    if (!(mask_rand[b] < 0.5f)) {
        const f4* xi = (const f4*)xrow;
        #pragma unroll
        for (int k = 0; k < 4; ++k)
            nt_store4(orow + 4 * (tid + NTHR * k), xi[tid + NTHR * k]);
        return;
    }

    __shared__ float2 sh_xf[XFSZ];       // (xp[t], fp[t]), padded
    __shared__ short  sh_seed[NSEED];    // q-group (4 q's) -> bracket segment
    __shared__ float  sh_wsum[NWAVE];    // per-wave scan totals

    // ---- span geometry ----
    const int t0 = tid * EPT;
    int idxA = t0 / 819;  if (idxA > 4) idxA = 4;
    int idxB = idxA + 1;  if (idxB > 4) idxB = 4;
    const float xlA = (float)idxA * HH;
    const float xlB = (float)idxB * HH;
    const float tb  = (float)((idxA + 1) * 819);   // first t belonging to span B

    // ---- all global loads issued up front ----
    float fpv[EPT];
    {
        #pragma unroll
        for (int q = 0; q < 4; ++q) {
            const f4 v = *(const f4*)(xrow + t0 + 4 * q);
            fpv[4 * q + 0] = v.x; fpv[4 * q + 1] = v.y;
            fpv[4 * q + 2] = v.z; fpv[4 * q + 3] = v.w;
        }
    }

    f4 cfA, cfB;
    if (TABLE) {
        cfA = tab[row * NSPAN + idxA];   // lanes share spans -> few lines/wave
        cfB = tab[row * NSPAN + idxB];
    } else {
        float y[NN], Mv[NN];
        f4 cf[NSPAN];
        spline_solve(yy, b, row % CC, y, Mv);
        horner_coefs(y, Mv, cf);
        cfA = cf[0];  cfB = cf[0];
        #pragma unroll
        for (int s = 1; s < NSPAN; ++s) {      // static indices -> cndmask
            if (idxA >= s) cfA = cf[s];
            if (idxB >= s) cfB = cf[s];
        }
    }

    // ---- curve + thread-local inclusive scan (in-place in xp[]) ----
    float xp[EPT + 1];
    float running = 0.0f;
    #pragma unroll
    for (int k = 0; k < EPT; ++k) {
        float ft = (float)(t0 + k);
        bool inB = ft >= tb;
        f4    cf = inB ? cfB : cfA;
        float xl = inB ? xlB : xlA;
        float s  = ft - xl;
        running += fmaf(s, fmaf(s, fmaf(s, cf.w, cf.z), cf.y), cf.x);
        xp[k] = running;
    }
    // curve at t0+EPT (for the lane-63 boundary reconstruction)
    float cN;
    {
        float ft = (float)(t0 + EPT);
        bool inB = ft >= tb;
        f4    cf = inB ? cfB : cfA;
        float xl = inB ? xlB : xlA;
        float s  = ft - xl;
        cN = fmaf(s, fmaf(s, fmaf(s, cf.w, cf.z), cf.y), cf.x);
    }

    // ---- wave scan (shfl) + cross-wave fixup (barrier 1) ----
    const int lane = tid & 63, wid = tid >> 6;
    float ws = running;
    #pragma unroll
    for (int d = 1; d < 64; d <<= 1) {
        float v = __shfl_up(ws, d, 64);
        if (lane >= d) ws += v;
    }
    if (lane == 63) sh_wsum[wid] = ws;
    __syncthreads();                            // B1
    float wo = 0.0f, total = 0.0f;
    #pragma unroll
    for (int w = 0; w < NWAVE; ++w) {           // ascending: order matters for
        float s = sh_wsum[w];                   // the lane-63 bit-exact proof
        total += s;
        if (w < wid) wo += s;
    }
    const float offs  = wo + (ws - running);    // exclusive prefix
    const float scale = 4095.0f / total;

    #pragma unroll
    for (int k = 0; k < EPT; ++k)
        xp[k] = (xp[k] + offs) * scale;

    // Boundary xp[EPT] without a barrier (validated in rounds 5/6):
    //  lanes 0..62: shfl_down of neighbor's xp[0] -> exact bits.
    //  lane 63: ((wo + ws) + cN) * scale == neighbor's (cN + wo')*scale
    //  bit-exactly (ascending sum + IEEE commutativity).
    {
        float n = __shfl_down(xp[0], 1, 64);
        float l = ((wo + ws) + cN) * scale;
        xp[EPT] = (lane == 63) ? l : n;         // tid NTHR-1: unused
    }

    // ---- publish (xp, fp) pairs ----
    #pragma unroll
    for (int k = 0; k < EPT; ++k)
        sh_xf[p2(t0 + k)] = make_float2(xp[k], fpv[k]);

    // ---- seed table: seed[m] = segment j with xp[j] <= 4m < xp[j+1] ----
    // *0.25f is an exponent shift (exact), so the invariant is bit-exact.
    // Avg trips: 1024 seeds / 4095 segments = 0.25 per segment.
    #pragma unroll
    for (int k = 0; k < EPT; ++k) {
        const int seg = t0 + k;
        if (seg < TT - 1) {
            float xa = xp[k], xb = xp[k + 1];
            int m = (int)ceilf(xa * 0.25f);  if (m < 0) m = 0;
            for (; m < NSEED && 4.0f * (float)m < xb; ++m)
                sh_seed[m] = (short)seg;
        }
    }
    if (tid == 0) {                             // head: 4m < xp[0] -> sentinel
        int mh = (int)ceilf(xp[0] * 0.25f);  if (mh > NSEED) mh = NSEED;
        for (int m = 0; m < mh; ++m) sh_seed[m] = (short)-1;
    }
    if (tid == NTHR - 1) {                      // tail: 4m >= xp[4095] -> last
        int mt = (int)ceilf(xp[EPT - 1] * 0.25f);  if (mt < 0) mt = 0;
        for (int m = mt; m < NSEED; ++m) sh_seed[m] = (short)(TT - 1);
    }
    __syncthreads();                            // B2: xf + seeds visible

    // ---- gather: 4 chunks of 4 consecutive q's, merge-walk from seed ----
    #pragma unroll
    for (int ch = 0; ch < 4; ++ch) {
        const int q0 = 4 * (tid + NTHR * ch);
        int j = sh_seed[q0 >> 2];               // xp[j] <= q0 guaranteed
        float2 cur = sh_xf[p2(j < 0 ? 0 : j)];
        if (j < 0) cur.x = -3.0e38f;            // head: fa == fp[0], slope->0
        int j1 = j + 1;  if (j1 > TT - 1) j1 = TT - 1;
        float2 nxt = sh_xf[p2(j1)];
        f4 res;
        #pragma unroll
        for (int e = 0; e < 4; ++e) {
            const float fq = (float)(q0 + e);
            while (j < TT - 1 && nxt.x <= fq) { // ~1 advance per q
                ++j;
                cur = nxt;
                if (j < TT - 1) nxt = sh_xf[p2(j + 1)];
            }
            float v;
            if (j >= TT - 1) {
                v = cur.y;                      // right clamp: fp[4095]
            } else {
                // cur.x <= fq < nxt.x -> d > 0 strictly
                float ratio = (fq - cur.x) * __builtin_amdgcn_rcpf(nxt.x - cur.x);
                v = fmaf(ratio, nxt.y - cur.y, cur.y);
            }
            if (e == 0) res.x = v;
            else if (e == 1) res.y = v;
            else if (e == 2) res.z = v;
            else res.w = v;
        }
        nt_store4(orow + q0, res);              // dense coalesced store
    }
}

extern "C" void kernel_launch(void* const* d_in, const int* in_sizes, int n_in,
                              void* d_out, int out_size, void* d_ws, size_t ws_size,
                              hipStream_t stream) {
    const float* x    = (const float*)d_in[0];   // (64,128,4096) fp32
    const float* yy   = (const float*)d_in[1];   // (64,6,128)    fp32
    const float* mask = (const float*)d_in[2];   // (64,1,1)      fp32
    float* out = (float*)d_out;                  // (64,128,4096) fp32

    if (d_ws != nullptr && ws_size >= TABBYTES) {
        f4* tab = (f4*)d_ws;
        spline_coef_kernel<<<dim3(NROW / 256), dim3(256), 0, stream>>>(yy, tab);
        timewarp_kernel<1><<<dim3(NROW), dim3(NTHR), 0, stream>>>(x, yy, mask, tab, out);
    } else {
        timewarp_kernel<0><<<dim3(NROW), dim3(NTHR), 0, stream>>>(x, yy, mask, nullptr, out);
    }
}

// Round 9
// 234.430 us; speedup vs baseline: 1.0307x; 1.0198x over previous
//
#include <hip/hip_runtime.h>

#define BB 64
#define CC 128
#define TT 4096
#define NN 6            // KNOT + 2
#define HH 819.0f       // (T-1)/(KNOT+1) = 4095/5, exact in fp32
#define NTHR 512
#define EPT 8           // curve elements per thread (NTHR*EPT == TT)
#define NWAVE (NTHR / 64)
#define NROW (BB * CC)
#define NSPAN 5
#define TABBYTES ((size_t)NROW * NSPAN * 16)
#define PADSZ (TT + TT / 32)
#define MAXE 4          // fixed predicated writes per segment (len>4 ~ never)

typedef float f4 __attribute__((ext_vector_type(4)));

__device__ __forceinline__ void nt_store4(float* p, f4 v) {
    __builtin_nontemporal_store(v, (f4*)p);
}

// LDS pad: +1 float per 32 breaks power-of-2 stride conflicts.
__device__ __forceinline__ int padi(int j) { return j + (j >> 5); }

// ---- 6x6 not-a-knot solve; A compile-time constant -> multipliers fold ----
__device__ __forceinline__ void spline_solve(const float* __restrict__ yy,
                                             int b, int c, float* y, float* Mv)
{
    #pragma unroll
    for (int k = 0; k < NN; ++k)
        y[k] = yy[((size_t)b * NN + k) * CC + c];
    float Aug[NN][NN + 1];
    #pragma unroll
    for (int i = 0; i < NN; ++i)
        #pragma unroll
        for (int j = 0; j < NN + 1; ++j)
            Aug[i][j] = 0.0f;
    Aug[0][0] = 1.0f;  Aug[0][1] = -2.0f;  Aug[0][2] = 1.0f;
    Aug[5][3] = 1.0f;  Aug[5][4] = -2.0f;  Aug[5][5] = 1.0f;
    #pragma unroll
    for (int i = 1; i < NN - 1; ++i) {
        Aug[i][i - 1] = HH / 6.0f;
        Aug[i][i]     = 2.0f * HH / 3.0f;
        Aug[i][i + 1] = HH / 6.0f;
        Aug[i][NN]    = (y[i + 1] - 2.0f * y[i] + y[i - 1]) / HH;
    }
    #pragma unroll
    for (int k = 0; k < NN; ++k) {
        float inv = 1.0f / Aug[k][k];
        #pragma unroll
        for (int i = k + 1; i < NN; ++i) {
            float m = Aug[i][k] * inv;
            #pragma unroll
            for (int j = k; j < NN + 1; ++j)
                Aug[i][j] -= m * Aug[k][j];
        }
    }
    #pragma unroll
    for (int i = NN - 1; i >= 0; --i) {
        float s = Aug[i][NN];
        #pragma unroll
        for (int j = i + 1; j < NN; ++j)
            s -= Aug[i][j] * Mv[j];
        Mv[i] = s / Aug[i][i];
    }
}

__device__ __forceinline__ void horner_coefs(const float* y, const float* Mv,
                                             f4* out5)
{
    const float invh  = 1.0f / HH;
    const float inv6h = 1.0f / (6.0f * HH);
    #pragma unroll
    for (int s = 0; s < NSPAN; ++s) {
        f4 cf;
        cf.x = y[s];
        cf.y = (y[s + 1] - y[s]) * invh - Mv[s] * (HH / 3.0f) - Mv[s + 1] * (HH / 6.0f);
        cf.z = Mv[s] * 0.5f;
        cf.w = (Mv[s + 1] - Mv[s]) * inv6h;
        out5[s] = cf;
    }
}

// ---- setup: per-(row, span) Horner coeffs (a,b,c,d) into workspace ----
__global__ __launch_bounds__(256) void spline_coef_kernel(
    const float* __restrict__ yy, f4* __restrict__ tab)
{
    const int row = blockIdx.x * 256 + threadIdx.x;   // 8192 rows, coalesced in c
    const int b = row / CC;
    const int c = row % CC;
    float y[NN], Mv[NN];
    spline_solve(yy, b, c, y, Mv);
    f4 cf[NSPAN];
    horner_coefs(y, Mv, cf);
    #pragma unroll
    for (int s = 0; s < NSPAN; ++s)
        tab[row * NSPAN + s] = cf[s];
}

// ============================ main kernel ==================================
// R4 structure (best measured) with the scatter's data-dependent loop
// replaced by a fixed 8x4 predicated write grid (straight-line code).
template <int TABLE>
__global__ __launch_bounds__(NTHR) void timewarp_kernel(
    const float* __restrict__ x,
    const float* __restrict__ yy,
    const float* __restrict__ mask_rand,
    const f4* __restrict__ tab,
    float* __restrict__ out)
{
    const int row = blockIdx.x;          // b*C + c
    const int b   = row / CC;
    const int tid = threadIdx.x;

    const float* xrow = x + (size_t)row * TT;
    float* orow       = out + (size_t)row * TT;

    // mask_rand >= 0.5 -> bit-exact copy (uniform per block)
    if (!(mask_rand[b] < 0.5f)) {
        const f4* xi = (const f4*)xrow;
        nt_store4(orow + 4 * tid,          xi[tid]);
        nt_store4(orow + 4 * (tid + NTHR), xi[tid + NTHR]);
        return;
    }

    __shared__ float sh_res[PADSZ];      // padded scatter target
    __shared__ float sh_wsum[NWAVE];     // per-wave scan totals

    // ---- span geometry ----
    const int t0 = tid * EPT;
    int idxA = t0 / 819;  if (idxA > 4) idxA = 4;
    int idxB = idxA + 1;  if (idxB > 4) idxB = 4;
    const float xlA = (float)idxA * HH;
    const float xlB = (float)idxB * HH;
    const float tb  = (float)((idxA + 1) * 819);   // first t belonging to span B

    // ---- all global loads issued up front ----
    const f4 v0 = *(const f4*)(xrow + t0);
    const f4 v1 = *(const f4*)(xrow + t0 + 4);
    // neighbor's first fp value, bit-identical bits from global (L1-hot)
    const float fpb = xrow[(t0 + EPT < TT) ? (t0 + EPT) : (TT - 1)];

    f4 cfA, cfB;
    if (TABLE) {
        cfA = tab[row * NSPAN + idxA];   // lanes share spans -> few lines/wave
        cfB = tab[row * NSPAN + idxB];
    } else {
        float y[NN], Mv[NN];
        f4 cf[NSPAN];
        spline_solve(yy, b, row % CC, y, Mv);
        horner_coefs(y, Mv, cf);
        cfA = cf[0];  cfB = cf[0];
        #pragma unroll
        for (int s = 1; s < NSPAN; ++s) {      // static indices -> cndmask
            if (idxA >= s) cfA = cf[s];
            if (idxB >= s) cfB = cf[s];
        }
    }

    float fpv[EPT];
    fpv[0] = v0.x; fpv[1] = v0.y; fpv[2] = v0.z; fpv[3] = v0.w;
    fpv[4] = v1.x; fpv[5] = v1.y; fpv[6] = v1.z; fpv[7] = v1.w;

    // ---- curve + thread-local inclusive scan (in-place in xp[]) ----
    float xp[EPT + 1];
    float running = 0.0f;
    #pragma unroll
    for (int k = 0; k < EPT; ++k) {
        float ft = (float)(t0 + k);
        bool inB = ft >= tb;
        f4    cf = inB ? cfB : cfA;
        float xl = inB ? xlB : xlA;
        float s  = ft - xl;
        running += fmaf(s, fmaf(s, fmaf(s, cf.w, cf.z), cf.y), cf.x);
        xp[k] = running;
    }
    // curve at t0+EPT (for the lane-63 boundary reconstruction)
    float cN;
    {
        float ft = (float)(t0 + EPT);
        bool inB = ft >= tb;
        f4    cf = inB ? cfB : cfA;
        float xl = inB ? xlB : xlA;
        float s  = ft - xl;
        cN = fmaf(s, fmaf(s, fmaf(s, cf.w, cf.z), cf.y), cf.x);
    }

    // ---- wave scan (shfl) + cross-wave fixup (barrier 1) ----
    const int lane = tid & 63, wid = tid >> 6;
    float ws = running;
    #pragma unroll
    for (int d = 1; d < 64; d <<= 1) {
        float v = __shfl_up(ws, d, 64);
        if (lane >= d) ws += v;
    }
    if (lane == 63) sh_wsum[wid] = ws;
    __syncthreads();                            // B1
    float wo = 0.0f, total = 0.0f;
    #pragma unroll
    for (int w = 0; w < NWAVE; ++w) {           // ascending: order matters for
        float s = sh_wsum[w];                   // the lane-63 bit-exact proof
        total += s;
        if (w < wid) wo += s;
    }
    const float offs  = wo + (ws - running);    // exclusive prefix
    const float scale = 4095.0f / total;

    #pragma unroll
    for (int k = 0; k < EPT; ++k)
        xp[k] = (xp[k] + offs) * scale;

    // Boundary xp[EPT] without a barrier (validated rounds 5-7):
    //  lanes 0..62: shfl_down of neighbor's xp[0] -> exact bits.
    //  lane 63: ((wo + ws) + cN) * scale == neighbor's (cN + wo')*scale
    //  bit-exactly (ascending fixup sum + IEEE commutativity).
    {
        float n = __shfl_down(xp[0], 1, 64);
        float l = ((wo + ws) + cN) * scale;
        xp[EPT] = (lane == 63) ? l : n;         // tid NTHR-1: unused
    }

    // ---- scatter: fixed 8x4 predicated write grid (straight-line) ----
    // segment j owns q in [ceil(xp[j]), ceil(xp[j+1])); len <= 4 essentially
    // always (warp derivative bounded); cold loop handles the remainder.
    #pragma unroll
    for (int k = 0; k < EPT; ++k) {
        const int seg = t0 + k;
        if (seg < TT - 1) {
            float xa = xp[k], xb = xp[k + 1];
            float fa = fpv[k];
            float fb = (k < EPT - 1) ? fpv[k + 1] : fpb;
            float d  = xb - xa;
            float slope = (d > 0.0f) ? (fb - fa) * __builtin_amdgcn_rcpf(d) : 0.0f;
            float a0 = fmaf(-xa, slope, fa);
            int qlo = (int)ceilf(xa);  if (qlo < 0) qlo = 0;
            int qhi = (int)ceilf(xb);  if (qhi > TT) qhi = TT;
            int len = qhi - qlo;
            #pragma unroll
            for (int e = 0; e < MAXE; ++e) {
                if (e < len)
                    sh_res[padi(qlo + e)] = fmaf((float)(qlo + e), slope, a0);
            }
            if (len > MAXE) {                   // cold: essentially never
                for (int q = qlo + MAXE; q < qhi; ++q)
                    sh_res[padi(q)] = fmaf((float)q, slope, a0);
            }
        }
    }
    if (tid == 0) {                             // head: q < xp[0] -> fp[0]
        int q1 = (int)ceilf(xp[0]);  if (q1 > TT) q1 = TT;
        for (int q = 0; q < q1; ++q) sh_res[padi(q)] = fpv[0];
    }
    if (tid == NTHR - 1) {                      // tail: q >= xp[4095] -> fp[4095]
        int q0 = (int)ceilf(xp[EPT - 1]);  if (q0 < 0) q0 = 0;
        for (int q = q0; q < TT; ++q) sh_res[padi(q)] = fpv[EPT - 1];
    }
    __syncthreads();                            // B2: sh_res complete

    // ---- restage: coalesced nontemporal float4 stores ----
    #pragma unroll
    for (int kk = 0; kk < 2; ++kk) {
        int i4  = tid + NTHR * kk;
        int fb4 = 4 * i4;
        int p   = padi(fb4);
        f4 v;
        v.x = sh_res[p + 0];
        v.y = sh_res[p + 1];
        v.z = sh_res[p + 2];
        v.w = sh_res[p + 3];
        nt_store4(orow + fb4, v);
    }
}

extern "C" void kernel_launch(void* const* d_in, const int* in_sizes, int n_in,
                              void* d_out, int out_size, void* d_ws, size_t ws_size,
                              hipStream_t stream) {
    const float* x    = (const float*)d_in[0];   // (64,128,4096) fp32
    const float* yy   = (const float*)d_in[1];   // (64,6,128)    fp32
    const float* mask = (const float*)d_in[2];   // (64,1,1)      fp32
    float* out = (float*)d_out;                  // (64,128,4096) fp32

    if (d_ws != nullptr && ws_size >= TABBYTES) {
        f4* tab = (f4*)d_ws;
        spline_coef_kernel<<<dim3(NROW / 256), dim3(256), 0, stream>>>(yy, tab);
        timewarp_kernel<1><<<dim3(NROW), dim3(NTHR), 0, stream>>>(x, yy, mask, tab, out);
    } else {
        timewarp_kernel<0><<<dim3(NROW), dim3(NTHR), 0, stream>>>(x, yy, mask, nullptr, out);
    }
}